// Round 1
// baseline (109.804 us; speedup 1.0000x reference)
//
#include <hip/hip_runtime.h>
#include <cmath>
#include <complex>
#include <algorithm>

// ---------------- path table (computed on host, passed as kernel arg) -------

#define SH_N 9
#define NB 128
#define NR 20
#define MAXP 96

struct PathTable {
    int off[SH_N + 1];          // per-output-SH-index path ranges
    float cg[MAXP];             // CG coefficient
    unsigned char i1[MAXP];     // dir SH index
    unsigned char i2[MAXP];     // neighbor-feature SH index
    unsigned char ldeg[MAXP];   // degree l of i1 (selects filter slice)
};

namespace {

double dfact(int n) { double r = 1.0; for (int i = 2; i <= n; ++i) r *= (double)i; return r; }

double cg_complex(int l1, int m1, int l2, int m2, int l3, int m3) {
    if (m3 != m1 + m2) return 0.0;
    if (l3 < std::abs(l1 - l2) || l3 > l1 + l2) return 0.0;
    double pre = std::sqrt((2.0 * l3 + 1.0) * dfact(l3 + l1 - l2) * dfact(l3 - l1 + l2)
                 * dfact(l1 + l2 - l3) / dfact(l1 + l2 + l3 + 1));
    pre *= std::sqrt(dfact(l3 + m3) * dfact(l3 - m3) * dfact(l1 - m1) * dfact(l1 + m1)
                 * dfact(l2 - m2) * dfact(l2 + m2));
    int kmin = std::max(0, std::max(l2 - l3 - m1, l1 - l3 + m2));
    int kmax = std::min(l1 + l2 - l3, std::min(l1 - m1, l2 + m2));
    double s = 0.0;
    for (int k = kmin; k <= kmax; ++k) {
        s += ((k & 1) ? -1.0 : 1.0) /
             (dfact(k) * dfact(l1 + l2 - l3 - k) * dfact(l1 - m1 - k) * dfact(l2 + m2 - k)
              * dfact(l3 - l2 + m1 + k) * dfact(l3 - l1 - m2 + k));
    }
    return pre * s;
}

void u_c2r(int l, std::complex<double> U[5][5]) {
    for (int i = 0; i < 5; ++i) for (int j = 0; j < 5; ++j) U[i][j] = {0.0, 0.0};
    U[l][l] = 1.0;
    const double isq = 1.0 / std::sqrt(2.0);
    for (int m = 1; m <= l; ++m) {
        double sgn = (m & 1) ? -1.0 : 1.0;
        U[l + m][l + m] = sgn * isq;
        U[l + m][l - m] = isq;
        U[l - m][l - m] = std::complex<double>(0.0, isq);
        U[l - m][l + m] = std::complex<double>(0.0, -sgn * isq);
    }
}

PathTable build_paths() {
    static double cgt[SH_N][SH_N][SH_N];
    for (auto& a : cgt) for (auto& b : a) for (auto& v : b) v = 0.0;
    for (int l1 = 0; l1 <= 2; ++l1)
    for (int l2 = 0; l2 <= 2; ++l2)
    for (int l3 = 0; l3 <= 2; ++l3) {
        if (((l1 + l2 + l3) & 1) || l3 < std::abs(l1 - l2) || l3 > l1 + l2) continue;
        std::complex<double> U1[5][5], U2[5][5], U3[5][5];
        u_c2r(l1, U1); u_c2r(l2, U2); u_c2r(l3, U3);
        const int n1 = 2 * l1 + 1, n2 = 2 * l2 + 1, n3 = 2 * l3 + 1;
        for (int i = 0; i < n1; ++i)
        for (int j = 0; j < n2; ++j)
        for (int k = 0; k < n3; ++k) {
            std::complex<double> s(0.0, 0.0);
            for (int a = 0; a < n1; ++a)
            for (int b = 0; b < n2; ++b)
            for (int c = 0; c < n3; ++c) {
                double B = cg_complex(l1, a - l1, l2, b - l2, l3, c - l3);
                if (B == 0.0) continue;
                s += B * U1[i][a] * U2[j][b] * std::conj(U3[k][c]);
            }
            double v = s.real();
            if (std::fabs(v) > 1e-12)
                cgt[l1 * l1 + i][l2 * l2 + j][l3 * l3 + k] = v;
        }
    }
    PathTable t{};
    int p = 0;
    for (int o = 0; o < SH_N; ++o) {
        t.off[o] = p;
        for (int a = 0; a < SH_N; ++a)
        for (int b = 0; b < SH_N; ++b) {
            double v = cgt[a][b][o];
            if (v != 0.0 && p < MAXP) {
                t.cg[p] = (float)v;
                t.i1[p] = (unsigned char)a;
                t.i2[p] = (unsigned char)b;
                t.ldeg[p] = (unsigned char)(a == 0 ? 0 : (a < 4 ? 1 : 2));
                ++p;
            }
        }
    }
    t.off[SH_N] = p;
    return t;
}

} // namespace

// ---------------- kernels ---------------------------------------------------

__global__ void zero_kernel(float* __restrict__ p, int n) {
    int i = (blockIdx.x * blockDim.x + threadIdx.x) * 4;
    if (i + 3 < n) {
        *reinterpret_cast<float4*>(p + i) = make_float4(0.f, 0.f, 0.f, 0.f);
    } else {
        for (int k = i; k < n; ++k) p[k] = 0.f;
    }
}

__global__ void __launch_bounds__(128)
so3_edge_kernel(const float* __restrict__ x,
                const float* __restrict__ radial,
                const float* __restrict__ dir,
                const float* __restrict__ cutoff,
                const float* __restrict__ Wf,
                const float* __restrict__ bf,
                const int* __restrict__ idx_i,
                const int* __restrict__ idx_j,
                float* __restrict__ y,
                PathTable pt,
                int E) {
    const int e = blockIdx.x;
    if (e >= E) return;
    const int c = threadIdx.x;             // basis channel, 0..127
    const int aj = idx_j[e];
    const int ai = idx_i[e];
    const float cut = cutoff[e];

    // radial filter: W[l][c] = (radial[e] @ Wf + bf)[l*NB+c] * cutoff
    float w0 = bf[c], w1 = bf[NB + c], w2 = bf[2 * NB + c];
    const float* rad = radial + e * NR;
    const float* wfc = Wf + c;
#pragma unroll
    for (int r = 0; r < NR; ++r) {
        const float rv = rad[r];                   // uniform -> scalar load
        const float* row = wfc + r * 3 * NB;
        w0 = fmaf(rv, row[0], w0);
        w1 = fmaf(rv, row[NB], w1);
        w2 = fmaf(rv, row[2 * NB], w2);
    }
    w0 *= cut; w1 *= cut; w2 *= cut;

    // stage neighbor features + direction SH into LDS
    __shared__ float s_xj[SH_N * NB];
    __shared__ float s_d[SH_N];
    const float* xr = x + (size_t)aj * (SH_N * NB) + c;
#pragma unroll
    for (int k = 0; k < SH_N; ++k) s_xj[k * NB + c] = xr[k * NB];
    if (c < SH_N) s_d[c] = dir[e * SH_N + c];
    __syncthreads();

    // CG path contraction, grouped by output SH index (static acc index)
    float* yo = y + (size_t)ai * (SH_N * NB) + c;
#pragma unroll
    for (int o = 0; o < SH_N; ++o) {
        float acc = 0.0f;
        const int p0 = pt.off[o], p1 = pt.off[o + 1];
        for (int p = p0; p < p1; ++p) {
            const int ld = pt.ldeg[p];
            const float wl = (ld == 0) ? w0 : ((ld == 1) ? w1 : w2);
            const float coef = pt.cg[p] * s_d[pt.i1[p]] * wl;
            acc = fmaf(coef, s_xj[pt.i2[p] * NB + c], acc);
        }
        atomicAdd(yo + o * NB, acc);
    }
}

// ---------------- launch ----------------------------------------------------

extern "C" void kernel_launch(void* const* d_in, const int* in_sizes, int n_in,
                              void* d_out, int out_size, void* d_ws, size_t ws_size,
                              hipStream_t stream) {
    const float* x      = (const float*)d_in[0];
    const float* radial = (const float*)d_in[1];
    const float* dir    = (const float*)d_in[2];
    const float* cutoff = (const float*)d_in[3];
    const float* Wf     = (const float*)d_in[4];
    const float* bf     = (const float*)d_in[5];
    const int*   idx_i  = (const int*)d_in[6];
    const int*   idx_j  = (const int*)d_in[7];
    float* y = (float*)d_out;
    const int E = in_sizes[6];

    static PathTable pt = build_paths();   // deterministic host-side constant

    const int n4 = (out_size + 3) / 4;
    zero_kernel<<<(n4 + 255) / 256, 256, 0, stream>>>(y, out_size);
    so3_edge_kernel<<<E, NB, 0, stream>>>(x, radial, dir, cutoff, Wf, bf,
                                          idx_i, idx_j, y, pt, E);
}